// Round 7
// baseline (4588.282 us; speedup 1.0000x reference)
//
#include <hip/hip_runtime.h>
#include <hip/hip_bf16.h>

#define N_NODES 40000
#define INIT_D  100
#define DD      200
#define FF      4
#define EE      800000
#define NRELS   800
#define BB      2048
#define H2D     100
#define FD      800   // F*D
#define RPAD    224   // padded r row (floats), zeros at 200..223
#define XPAD    256   // byte pad after fp8 x / kw buffers (zeroed for x)

typedef __hip_bfloat16 bf16;
typedef unsigned char u8;
typedef unsigned short u16;
typedef unsigned int u32;
typedef float floatx2 __attribute__((ext_vector_type(2)));
typedef float floatx4 __attribute__((ext_vector_type(4)));
typedef u32 u32x2 __attribute__((ext_vector_type(2)));
typedef short bshort8 __attribute__((ext_vector_type(8)));   // 8 bf16 for MFMA A/B

#define XSCALE 256.f
#define XINV   (1.f / 256.f)

__device__ __forceinline__ float b2f(bf16 v) { return __bfloat162float(v); }

__device__ __forceinline__ void fp8x4_dec(u32 q, float* o) {
    floatx2 lo = __builtin_amdgcn_cvt_pk_f32_fp8((int)q, false);
    floatx2 hi = __builtin_amdgcn_cvt_pk_f32_fp8((int)q, true);
    o[0] = lo.x; o[1] = lo.y; o[2] = hi.x; o[3] = hi.y;
}

__device__ __forceinline__ u32 fp8x4_enc(float v0, float v1, float v2, float v3) {
    int o = 0;
    o = __builtin_amdgcn_cvt_pk_fp8_f32(v0, v1, o, false);
    o = __builtin_amdgcn_cvt_pk_fp8_f32(v2, v3, o, true);
    return (u32)o;
}

// sum over each 16-lane group via DPP (pure VALU, no LDS pipe).
__device__ __forceinline__ float red16(float v) {
    int t;
    t = __builtin_amdgcn_update_dpp(0, __float_as_int(v), 0xB1, 0xF, 0xF, true);
    v += __int_as_float(t);
    t = __builtin_amdgcn_update_dpp(0, __float_as_int(v), 0x4E, 0xF, 0xF, true);
    v += __int_as_float(t);
    t = __builtin_amdgcn_update_dpp(0, __float_as_int(v), 0x124, 0xF, 0xF, true);
    v += __int_as_float(t);
    t = __builtin_amdgcn_update_dpp(0, __float_as_int(v), 0x128, 0xF, 0xF, true);
    v += __int_as_float(t);
    return v;
}

// fp8x8 (two u32) -> bf16x8 (exact: e4m3 subset of bf16)
__device__ __forceinline__ bshort8 fp8x8_bf16(u32x2 q) {
    float f[8];
    fp8x4_dec(q.x, f); fp8x4_dec(q.y, f + 4);
    bshort8 r;
#pragma unroll
    for (int j = 0; j < 8; j++) r[j] = (short)(__float_as_uint(f[j]) >> 16);
    return r;
}

// ---------------- setup ----------------
__global__ __launch_bounds__(256) void zero_kernel(int* count, double* loss, u8* pad0, u8* pad1) {
    int idx = blockIdx.x * 256 + threadIdx.x;
    if (idx < N_NODES) count[idx] = 0;
    if (idx == 0) *loss = 0.0;
    if (idx < 64 && pad0) ((u32*)pad0)[idx] = 0u;
    if (idx < 64 && pad1) ((u32*)pad1)[idx] = 0u;
}

// ---------------- x0 = tanh(init_embed @ pca_w + pca_b) ----------------
__global__ __launch_bounds__(64) void pca_kernel(const float* __restrict__ emb,
                                                 const float* __restrict__ pw,
                                                 const float* __restrict__ pb,
                                                 u8* __restrict__ xq,
                                                 float* __restrict__ xf,
                                                 int mode) {
    __shared__ float es[INIT_D][18];
    int r0 = blockIdx.y * 16;
    int c  = blockIdx.x * 64 + threadIdx.x;
    for (int idx = threadIdx.x; idx < 16 * INIT_D; idx += 64) {
        int r = idx / INIT_D, k = idx % INIT_D;
        es[k][r] = emb[(size_t)(r0 + r) * INIT_D + k];
    }
    __syncthreads();
    if (c >= FD) return;
    floatx2 acc[8];
#pragma unroll
    for (int i = 0; i < 8; i++) acc[i] = (floatx2){0.f, 0.f};
    for (int k = 0; k < INIT_D; k++) {
        float w = pw[k * FD + c];
        floatx2 w2 = (floatx2){w, w};
#pragma unroll
        for (int i = 0; i < 8; i++) acc[i] += *(const floatx2*)&es[k][2 * i] * w2;
    }
    float bias = pb[c];
#pragma unroll
    for (int r = 0; r < 16; r++) {
        float a = (r & 1) ? acc[r >> 1].y : acc[r >> 1].x;
        float v = tanhf(a + bias);
        if (mode == 0) {
            int t8 = __builtin_amdgcn_cvt_pk_fp8_f32(v * XSCALE, 0.f, 0, false);
            xq[(size_t)(r0 + r) * FD + c] = (u8)(t8 & 0xFF);
        } else {
            xf[(size_t)(r0 + r) * FD + c] = v;
        }
    }
}

// ---------------- B-pack: cw -> MFMA B-fragments, s-major for LDS staging -------
// bp layout [s][t][hl][lane][8] u16: index (((s*13+t)*2+hl)*64+lane)*8.
// B[k][col]: col = t*16 + (lane&15), k = s*32 + (lane>>4)*8 + j; zero outside 200x200.
__global__ __launch_bounds__(256) void bpack_kernel(const float* __restrict__ cw,
                                                    u16* __restrict__ bp) {
    int w = (blockIdx.x * 256 + threadIdx.x) >> 6;
    int lane = threadIdx.x & 63;
    if (w >= 91) return;
    int t = w / 7, s = w % 7;
    int col = t * 16 + (lane & 15);
    int g = lane >> 4;
    bshort8 hv, lv;
#pragma unroll
    for (int j = 0; j < 8; j++) {
        int k = s * 32 + g * 8 + j;
        float v = (k < DD && col < DD) ? cw[k * DD + col] : 0.f;
        u32 b = __float_as_uint(v);
        u32 rb = b + 0x7FFFu + ((b >> 16) & 1u);
        u16 h = (u16)(rb >> 16);
        float hf = __uint_as_float(((u32)h) << 16);
        float lo = v - hf;
        u32 lb = __float_as_uint(lo);
        lb += 0x7FFFu + ((lb >> 16) & 1u);
        hv[j] = (short)h;
        lv[j] = (short)(lb >> 16);
    }
    size_t base = ((size_t)((s * 13 + t) * 2) * 64 + lane) * 8;
    *(bshort8*)(bp + base) = hv;          // hl = 0 (hi)
    *(bshort8*)(bp + base + 512) = lv;    // hl = 1 (lo)
}

// ---------------- kw via MFMA + LDS-staged B ----------------
// Per s-step the block stages the 26 KB B-slab (13 t x hi/lo) into LDS once;
// all 4 waves consume from LDS. Same MFMA order as round-3 -> identical numerics.
__global__ __launch_bounds__(256) void kw_mfma(const u8* __restrict__ xq,
                                               const u16* __restrict__ bp,
                                               u8* __restrict__ kwout) {
    __shared__ u16 bs[13312];   // 26,624 B = 13 t x 2 x 64 x 8 u16
    int wv = threadIdx.x >> 6, lane = threadIdx.x & 63;
    int Mbase = blockIdx.x * 128 + wv * 32;
    int g = lane >> 4, c16 = lane & 15;
    floatx4 acc[2][13];
#pragma unroll
    for (int m = 0; m < 2; m++)
#pragma unroll
        for (int t = 0; t < 13; t++) acc[m][t] = (floatx4){0.f, 0.f, 0.f, 0.f};

    const u8* a0p = xq + (size_t)(Mbase + c16) * DD + g * 8;
    const u8* a1p = a0p + 16 * DD;
    u32x2 qa = *(const u32x2*)a0p;
    u32x2 qb = *(const u32x2*)a1p;

    for (int s = 0; s < 7; s++) {
        __syncthreads();   // prior compute done before overwrite
        const floatx4* gs = (const floatx4*)(bp + (size_t)s * 13312);
        floatx4* ld = (floatx4*)bs;
        for (int i = threadIdx.x; i < 1664; i += 256) ld[i] = gs[i];
        __syncthreads();
        bshort8 a0 = fp8x8_bf16(qa);
        bshort8 a1 = fp8x8_bf16(qb);
        if (s < 6) {   // 1-deep A prefetch, overlaps the MFMA block
            qa = *(const u32x2*)(a0p + (s + 1) * 32);
            qb = *(const u32x2*)(a1p + (s + 1) * 32);
        }
#pragma unroll
        for (int t = 0; t < 13; t++) {
            const u16* tb = bs + t * 1024;
            bshort8 bh = *(const bshort8*)(tb + lane * 8);
            bshort8 bl = *(const bshort8*)(tb + 512 + lane * 8);
            acc[0][t] = __builtin_amdgcn_mfma_f32_16x16x32_bf16(a0, bh, acc[0][t], 0, 0, 0);
            acc[1][t] = __builtin_amdgcn_mfma_f32_16x16x32_bf16(a1, bh, acc[1][t], 0, 0, 0);
            acc[0][t] = __builtin_amdgcn_mfma_f32_16x16x32_bf16(a0, bl, acc[0][t], 0, 0, 0);
            acc[1][t] = __builtin_amdgcn_mfma_f32_16x16x32_bf16(a1, bl, acc[1][t], 0, 0, 0);
        }
    }

    int rq = g * 4;
#pragma unroll
    for (int m = 0; m < 2; m++) {
#pragma unroll
        for (int t = 0; t < 13; t++) {
            int col = t * 16 + c16;
            if (col >= DD) continue;
            floatx4 a = acc[m][t];
            float v0 = a.x * XINV, v1 = a.y * XINV, v2 = a.z * XINV, v3 = a.w * XINV;
            v0 = v0 > 0.f ? v0 : 0.2f * v0;
            v1 = v1 > 0.f ? v1 : 0.2f * v1;
            v2 = v2 > 0.f ? v2 : 0.2f * v2;
            v3 = v3 > 0.f ? v3 : 0.2f * v3;
            float mx = fmaxf(fmaxf(v0, v1), fmaxf(v2, v3));
            float e0 = __expf(v0 - mx), e1 = __expf(v1 - mx);
            float e2 = __expf(v2 - mx), e3 = __expf(v3 - mx);
            float inv = 1.f / (e0 + e1 + e2 + e3);
            size_t base = (size_t)(Mbase + m * 16 + rq) * DD + col;
            kwout[base]           = (u8)(e0 * inv * 255.f + 0.5f);
            kwout[base + DD]      = (u8)(e1 * inv * 255.f + 0.5f);
            kwout[base + 2 * DD]  = (u8)(e2 * inv * 255.f + 0.5f);
            kwout[base + 3 * DD]  = (u8)(e3 * inv * 255.f + 0.5f);
        }
    }
}

// ---------------- kw fallback: wave-per-node, f32 x ----------------
__global__ __launch_bounds__(256) void kw_old(const float* __restrict__ x,
                                              const float* __restrict__ cw,
                                              u8* __restrict__ kw) {
    int wave = threadIdx.x >> 6, lane = threadIdx.x & 63;
    int n = blockIdx.x * 4 + wave;
    const float* xp = x + (size_t)n * FD;
    float acc[4][4];
#pragma unroll
    for (int f = 0; f < 4; f++)
#pragma unroll
        for (int i = 0; i < 4; i++) acc[f][i] = 0.f;
    for (int k = 0; k < DD; k++) {
        float xv0 = xp[k], xv1 = xp[DD + k];
        float xv2 = xp[2 * DD + k], xv3 = xp[3 * DD + k];
#pragma unroll
        for (int i = 0; i < 4; i++) {
            int d = i * 64 + lane;
            float w = (d < DD) ? cw[k * DD + d] : 0.f;
            acc[0][i] += xv0 * w; acc[1][i] += xv1 * w;
            acc[2][i] += xv2 * w; acc[3][i] += xv3 * w;
        }
    }
    u8* kwp = kw + (size_t)n * FD;
#pragma unroll
    for (int i = 0; i < 4; i++) {
        int d = i * 64 + lane;
        if (d >= DD) continue;
        float v0 = acc[0][i], v1 = acc[1][i], v2 = acc[2][i], v3 = acc[3][i];
        v0 = v0 > 0.f ? v0 : 0.2f * v0;
        v1 = v1 > 0.f ? v1 : 0.2f * v1;
        v2 = v2 > 0.f ? v2 : 0.2f * v2;
        v3 = v3 > 0.f ? v3 : 0.2f * v3;
        float m = fmaxf(fmaxf(v0, v1), fmaxf(v2, v3));
        float e0 = __expf(v0 - m), e1 = __expf(v1 - m), e2 = __expf(v2 - m), e3 = __expf(v3 - m);
        float inv = 1.f / (e0 + e1 + e2 + e3);
        kwp[d]          = (u8)(e0 * inv * 255.f + 0.5f);
        kwp[DD + d]     = (u8)(e1 * inv * 255.f + 0.5f);
        kwp[2 * DD + d] = (u8)(e2 * inv * 255.f + 0.5f);
        kwp[3 * DD + d] = (u8)(e3 * inv * 255.f + 0.5f);
    }
}

// ---------------- CSR build (packed: etype<<16 | src) ----------------
__global__ __launch_bounds__(256) void count_kernel(const int* __restrict__ dst, int* count) {
    int e = blockIdx.x * 256 + threadIdx.x;
    atomicAdd(&count[dst[e]], 1);
}

// shfl-based scan; also zeroes count[] so it can be reused as the scatter cursor.
__global__ __launch_bounds__(1024) void scan_kernel(int* __restrict__ count, int* __restrict__ offs) {
    __shared__ int wsums[16];
    __shared__ int carry_s;
    int tid = threadIdx.x;
    int wv = tid >> 6, lane = tid & 63;
    if (tid == 0) { carry_s = 0; offs[0] = 0; }
    __syncthreads();
    for (int base = 0; base < 40960; base += 1024) {
        int i = base + tid;
        int v = (i < N_NODES) ? count[i] : 0;
        if (i < N_NODES) count[i] = 0;
        int x = v;
#pragma unroll
        for (int off = 1; off < 64; off <<= 1) {
            int y = __shfl_up(x, off, 64);
            if (lane >= off) x += y;
        }
        if (lane == 63) wsums[wv] = x;
        __syncthreads();
        if (wv == 0) {
            int s = (lane < 16) ? wsums[lane] : 0;
#pragma unroll
            for (int off = 1; off < 16; off <<= 1) {
                int y = __shfl_up(s, off, 64);
                if (lane >= off) s += y;
            }
            if (lane < 16) wsums[lane] = s;
        }
        __syncthreads();
        int add = carry_s + (wv > 0 ? wsums[wv - 1] : 0);
        int incl = x + add;
        if (i < N_NODES) offs[i + 1] = incl;
        __syncthreads();
        if (tid == 1023) carry_s = incl;
        __syncthreads();
    }
}

__global__ __launch_bounds__(256) void scatter_kernel(const int* __restrict__ src,
                                                      const int* __restrict__ dst,
                                                      const int* __restrict__ etyp,
                                                      const int* __restrict__ offs,
                                                      int* cursor,
                                                      u32* __restrict__ ep) {
    int e = blockIdx.x * 256 + threadIdx.x;
    int d = dst[e];
    int p = offs[d] + atomicAdd(&cursor[d], 1);
    ep[p] = ((u32)etyp[e] << 16) | (u32)src[e];
}

// ---------------- r padding ----------------
__global__ __launch_bounds__(256) void r0pad_kernel(const float* __restrict__ r0,
                                                    float* __restrict__ rp) {
    int idx = blockIdx.x * 256 + threadIdx.x;   // 800*224 = 179200 exactly
    int n = idx / RPAD, d = idx % RPAD;
    rp[idx] = (d < DD) ? r0[n * DD + d] : 0.f;
}

__global__ __launch_bounds__(256) void rmul_kernel(const float* __restrict__ r0,
                                                   const float* __restrict__ w,
                                                   float* __restrict__ r1) {
    __shared__ float row[DD];
    int n = blockIdx.x;
    if (threadIdx.x < DD) row[threadIdx.x] = r0[n * DD + threadIdx.x];
    __syncthreads();
    int d = threadIdx.x;
    if (d < DD) {
        float acc = 0.f;
        for (int k = 0; k < DD; k++) acc += row[k] * w[k * DD + d];
        r1[n * RPAD + d] = acc;
    } else if (d < RPAD) {
        r1[n * RPAD + d] = 0.f;
    }
}

// ---------------- fast agg: 16-lane f-groups, scalar edge broadcast, 2-slot pipe --
// (round-3 version, benched 223 us/layer; launch_bounds pins VGPR<=64 / 8 waves/EU)
__global__ __launch_bounds__(256, 8) void agg_fp8(const u8* __restrict__ xin,
                                                  const u8* __restrict__ kwv,
                                                  const float* __restrict__ r,
                                                  const int* __restrict__ offs,
                                                  const u32* __restrict__ ep,
                                                  u8* __restrict__ xoq,
                                                  float* __restrict__ xof,
                                                  int mode) {
    int n    = blockIdx.x * 4 + (threadIdx.x >> 6);   // 40000 waves
    int lane = threadIdx.x & 63;
    int f    = lane >> 4;
    int k    = lane & 15;
    bool act = k < 13;
    int xoff = f * DD + k * 16;
    int roffc = k * 16; if (roffc > 200) roffc = 200;   // lanes 13..15 -> zero pad

    float xdf[16];
    {
        const u8* xdp = xin + (size_t)n * FD + xoff;
        u32x2 a = *(const u32x2*)xdp;
        u32x2 b = *(const u32x2*)(xdp + 8);
        fp8x4_dec(a.x, xdf); fp8x4_dec(a.y, xdf + 4);
        fp8x4_dec(b.x, xdf + 8); fp8x4_dec(b.y, xdf + 12);
    }
    floatx2 xd2[8];
#pragma unroll
    for (int j = 0; j < 8; j++) xd2[j] = (floatx2){xdf[2 * j], xdf[2 * j + 1]};

    floatx2 A[8];
#pragma unroll
    for (int j = 0; j < 8; j++) A[j] = (floatx2){0.f, 0.f};
    float Sm = 0.f;

    int e0 = offs[n], e1 = offs[n + 1];

#define ISSUE(QA, QB, R0, R1, R2, R3, JJ) do {                                  \
    u32 wrd_ = (u32)__builtin_amdgcn_readlane((int)epv, (JJ));                  \
    int s_ = (int)(wrd_ & 0xFFFFu), t_ = (int)(wrd_ >> 16);                     \
    const u8* xsp_ = xin + (size_t)s_ * FD;                                     \
    const float* rp_ = r + (size_t)t_ * RPAD + roffc;                           \
    QA = *(const u32x2*)(xsp_ + xoff);                                          \
    QB = *(const u32x2*)(xsp_ + xoff + 8);                                      \
    const floatx4* r4_ = (const floatx4*)rp_;                                   \
    R0 = r4_[0]; R1 = r4_[1]; R2 = r4_[2]; R3 = r4_[3];                         \
} while (0)

#define COMPUTE(QA, QB, R0, R1, R2, R3) do {                                    \
    float xsf_[16];                                                             \
    fp8x4_dec(QA.x, xsf_);     fp8x4_dec(QA.y, xsf_ + 4);                       \
    fp8x4_dec(QB.x, xsf_ + 8); fp8x4_dec(QB.y, xsf_ + 12);                      \
    floatx2 rr_[8];                                                             \
    rr_[0] = (floatx2){R0.x, R0.y}; rr_[1] = (floatx2){R0.z, R0.w};             \
    rr_[2] = (floatx2){R1.x, R1.y}; rr_[3] = (floatx2){R1.z, R1.w};             \
    rr_[4] = (floatx2){R2.x, R2.y}; rr_[5] = (floatx2){R2.z, R2.w};             \
    rr_[6] = (floatx2){R3.x, R3.y}; rr_[7] = (floatx2){R3.z, R3.w};             \
    floatx2 mm_[8];                                                             \
    floatx2 ps_ = (floatx2){0.f, 0.f};                                          \
    _Pragma("unroll")                                                           \
    for (int j_ = 0; j_ < 8; j_++) {                                            \
        floatx2 xs2_ = (floatx2){xsf_[2 * j_], xsf_[2 * j_ + 1]};               \
        mm_[j_] = xs2_ * rr_[j_];                                               \
        ps_ += mm_[j_] * xd2[j_];                                               \
    }                                                                           \
    float p_ = red16(ps_.x + ps_.y);                                            \
    float q_ = p_ * (XINV * XINV);                                              \
    float lg_ = fmaxf(q_, 0.2f * q_);                                           \
    float wg_ = __expf(lg_);                                                    \
    Sm += wg_;                                                                  \
    floatx2 w2_ = (floatx2){wg_, wg_};                                          \
    _Pragma("unroll")                                                           \
    for (int j_ = 0; j_ < 8; j_++) A[j_] += w2_ * mm_[j_];                      \
} while (0)

    for (int cb = e0; cb < e1; cb += 64) {
        int cnt = e1 - cb; if (cnt > 64) cnt = 64;
        u32 epv = ep[cb + (lane < cnt ? lane : cnt - 1)];
        u32x2 qaA, qbA, qaB, qbB;
        floatx4 rA0, rA1, rA2, rA3, rB0, rB1, rB2, rB3;
        ISSUE(qaA, qbA, rA0, rA1, rA2, rA3, 0);
        if (cnt > 1) ISSUE(qaB, qbB, rB0, rB1, rB2, rB3, 1);
        int m2 = cnt & ~1;
        for (int ii = 0; ii < m2; ii += 2) {
            COMPUTE(qaA, qbA, rA0, rA1, rA2, rA3);
            if (ii + 2 < cnt) ISSUE(qaA, qbA, rA0, rA1, rA2, rA3, ii + 2);
            COMPUTE(qaB, qbB, rB0, rB1, rB2, rB3);
            if (ii + 3 < cnt) ISSUE(qaB, qbB, rB0, rB1, rB2, rB3, ii + 3);
        }
        if (cnt & 1) COMPUTE(qaA, qbA, rA0, rA1, rA2, rA3);
    }
#undef ISSUE
#undef COMPUTE

    float inv = 1.f / (Sm + 1e-16f);
    u32 kws[4];
    {
        const u8* kwp = kwv + (size_t)n * FD + xoff;
        u32x2 ka = *(const u32x2*)kwp;
        u32x2 kb = *(const u32x2*)(kwp + 8);
        kws[0] = ka.x; kws[1] = ka.y; kws[2] = kb.x; kws[3] = kb.y;
    }
    float v[16];
#pragma unroll
    for (int j = 0; j < 16; j++) {
        float kv = (float)((kws[j >> 2] >> ((j & 3) * 8)) & 0xFF) * (1.f / 255.f);
        float Aj = (j & 1) ? A[j >> 1].y : A[j >> 1].x;
        v[j] = tanhf(Aj * inv * XINV) * kv;   // A scaled by S
    }
    if (mode == 0) {
        if (act) {
            u32 o0 = fp8x4_enc(v[0] * XSCALE, v[1] * XSCALE, v[2] * XSCALE, v[3] * XSCALE);
            u32 o1 = fp8x4_enc(v[4] * XSCALE, v[5] * XSCALE, v[6] * XSCALE, v[7] * XSCALE);
            u32 o2 = fp8x4_enc(v[8] * XSCALE, v[9] * XSCALE, v[10] * XSCALE, v[11] * XSCALE);
            u32 o3 = fp8x4_enc(v[12] * XSCALE, v[13] * XSCALE, v[14] * XSCALE, v[15] * XSCALE);
            u8* op = xoq + (size_t)n * FD + xoff;
            *(u32x2*)op = (u32x2){o0, o1};
            if (k < 12) *(u32x2*)(op + 8) = (u32x2){o2, o3};
        }
    } else {
        if (act) {
            float* op = xof + (size_t)n * FD + xoff;
            *(floatx4*)op       = (floatx4){v[0], v[1], v[2], v[3]};
            *(floatx4*)(op + 4) = (floatx4){v[4], v[5], v[6], v[7]};
            if (k < 12) {
                *(floatx4*)(op + 8)  = (floatx4){v[8], v[9], v[10], v[11]};
                *(floatx4*)(op + 12) = (floatx4){v[12], v[13], v[14], v[15]};
            }
        }
    }
}

// ---------------- fallback sliced agg (f32, RPAD-strided r) + copyback ----------------
__global__ __launch_bounds__(256) void agg_sliced(const float* __restrict__ xall,
                                                  const u8* __restrict__ kw,
                                                  const float* __restrict__ r,
                                                  const int* __restrict__ offs,
                                                  const u32* __restrict__ ep,
                                                  bf16* __restrict__ xtmp,
                                                  int f) {
    int n    = blockIdx.x * 4 + (threadIdx.x >> 6);
    int lane = threadIdx.x & 63;
    const float* xdp = xall + (size_t)n * FD + f * DD;
    float xd[4];
#pragma unroll
    for (int i = 0; i < 4; i++) {
        int d = i * 64 + lane;
        xd[i] = (d < DD) ? xdp[d] : 0.f;
    }
    float M = -INFINITY, S = 0.f;
    float A0 = 0.f, A1 = 0.f, A2 = 0.f, A3 = 0.f;
    int e0 = offs[n], e1 = offs[n + 1];
    for (int e = e0; e < e1; ++e) {
        u32 wrd = ep[e];
        int s = wrd & 0xFFFF, t = wrd >> 16;
        const float* xsp = xall + (size_t)s * FD + f * DD;
        const float* rp = r + (size_t)t * RPAD;
        float mm[4];
        float p = 0.f;
#pragma unroll
        for (int i = 0; i < 4; i++) {
            int d = i * 64 + lane;
            float xs = (d < DD) ? xsp[d] : 0.f;
            float rrv = (d < DD) ? rp[d] : 0.f;
            mm[i] = xs * rrv;
            p += mm[i] * xd[i];
        }
#pragma unroll
        for (int o = 32; o > 0; o >>= 1) p += __shfl_xor(p, o, 64);
        float logit = p > 0.f ? p : 0.2f * p;
        float nm = fmaxf(M, logit);
        float sc = __expf(M - nm);
        float w  = __expf(logit - nm);
        S  = S * sc + w;
        A0 = A0 * sc + w * mm[0];
        A1 = A1 * sc + w * mm[1];
        A2 = A2 * sc + w * mm[2];
        A3 = A3 * sc + w * mm[3];
        M = nm;
    }
    float inv = 1.f / (S + 1e-16f);
    const u8* kwp = kw + (size_t)n * FD + f * DD;
    bf16* xo = xtmp + (size_t)n * DD;
    float A[4] = {A0, A1, A2, A3};
#pragma unroll
    for (int i = 0; i < 4; i++) {
        int d = i * 64 + lane;
        if (d < DD) {
            float kv = (float)kwp[d] * (1.f / 255.f);
            xo[d] = __float2bfloat16(tanhf(A[i] * inv) * kv);
        }
    }
}

__global__ __launch_bounds__(256) void copyback_kernel(const bf16* __restrict__ xtmp,
                                                       float* __restrict__ xall, int f) {
    int idx = blockIdx.x * 256 + threadIdx.x;   // 8,000,000
    int n = idx / DD, d = idx % DD;
    xall[(size_t)n * FD + f * DD + d] = b2f(xtmp[idx]);
}

// ---------------- outputs (f32) ----------------
__global__ __launch_bounds__(256) void subemb_kernel(const float* __restrict__ x,
                                                     const int* __restrict__ sub,
                                                     float* __restrict__ out) {
    int idx = blockIdx.x * 256 + threadIdx.x;   // 1,638,400
    int b = idx / FD, c = idx % FD;
    out[idx] = x[(size_t)sub[b] * FD + c];
}

__global__ __launch_bounds__(256) void relemb_kernel(const float* __restrict__ ir,
                                                     const int* __restrict__ rel,
                                                     float* __restrict__ out) {
    int idx = blockIdx.x * 256 + threadIdx.x;   // 1,638,400
    int b = idx / FD, d = idx % DD;
    out[idx] = ir[(size_t)rel[b] * DD + d];
}

// ---------------- CLUB loss: 2 rows/block, mu/lv phase-1 in parallel ----------
__global__ __launch_bounds__(256) void club_kernel(const float* __restrict__ se,
                                                   const int* __restrict__ perm,
                                                   const float* __restrict__ mu_w1, const float* __restrict__ mu_b1,
                                                   const float* __restrict__ mu_w2, const float* __restrict__ mu_b2,
                                                   const float* __restrict__ lv_w1, const float* __restrict__ lv_b1,
                                                   const float* __restrict__ lv_w2, const float* __restrict__ lv_b2,
                                                   double* loss) {
    const int PI[6] = {0, 0, 0, 1, 1, 2};
    const int PJ[6] = {1, 2, 3, 2, 3, 3};
    int p = blockIdx.y;
    int i = PI[p], j = PJ[p];
    __shared__ float xi[DD], yj[DD], yjp[DD], h1m[H2D], h1v[H2D];
    __shared__ float wsum[4];
    float psum = 0.f;
    int tid = threadIdx.x;
    for (int rr = 0; rr < 2; ++rr) {
        int b = blockIdx.x * 2 + rr;
        int bp = perm[b];
        if (tid < DD) {
            xi[tid]  = se[(size_t)b * FD + i * DD + tid];
            yj[tid]  = se[(size_t)b * FD + j * DD + tid];
            yjp[tid] = se[(size_t)bp * FD + j * DD + tid];
        }
        __syncthreads();
        if (tid < H2D) {
            int c = tid;
            float a1 = mu_b1[p * H2D + c];
            for (int d = 0; d < DD; d++)
                a1 += xi[d] * mu_w1[(size_t)p * DD * H2D + d * H2D + c];
            h1m[c] = fmaxf(a1, 0.f);
        } else if (tid >= 128 && tid < 128 + H2D) {
            int c = tid - 128;
            float a2 = lv_b1[p * H2D + c];
            for (int d = 0; d < DD; d++)
                a2 += xi[d] * lv_w1[(size_t)p * DD * H2D + d * H2D + c];
            h1v[c] = fmaxf(a2, 0.f);
        }
        __syncthreads();
        if (tid < DD) {
            int d = tid;
            float m = mu_b2[p * DD + d];
            float v = lv_b2[p * DD + d];
            for (int c = 0; c < H2D; c++) {
                m += h1m[c] * mu_w2[(size_t)p * H2D * DD + c * DD + d];
                v += h1v[c] * lv_w2[(size_t)p * H2D * DD + c * DD + d];
            }
            float lv = tanhf(v);
            float ivr = __expf(-lv);
            float d1 = m - yj[d], d2 = m - yjp[d];
            psum += (d2 * d2 - d1 * d1) * ivr;
        }
        __syncthreads();
    }
    float v = psum;
#pragma unroll
    for (int o = 32; o > 0; o >>= 1) v += __shfl_xor(v, o, 64);
    if ((tid & 63) == 0) wsum[tid >> 6] = v;
    __syncthreads();
    if (tid == 0) {
        double t = (double)wsum[0] + (double)wsum[1] + (double)wsum[2] + (double)wsum[3];
        atomicAdd(loss, t / (2.0 * (double)BB));
    }
}

__global__ void loss_out_kernel(const double* loss, float* out) {
    if (threadIdx.x == 0 && blockIdx.x == 0)
        out[0] = (float)(*loss);
}

// ---------------- launch ----------------
extern "C" void kernel_launch(void* const* d_in, const int* in_sizes, int n_in,
                              void* d_out, int out_size, void* d_ws, size_t ws_size,
                              hipStream_t stream) {
    const int* sub  = (const int*)d_in[0];
    const int* rel  = (const int*)d_in[1];
    const int* eidx = (const int*)d_in[2];
    const int* etyp = (const int*)d_in[3];
    const int* perm = (const int*)d_in[4];
    const float* init_embed = (const float*)d_in[5];
    const float* init_rel   = (const float*)d_in[6];
    const float* pca_w = (const float*)d_in[7];
    const float* pca_b = (const float*)d_in[8];
    const float* cw_w  = (const float*)d_in[9];
    const float* w_rel = (const float*)d_in[10];
    const float* mu_w1 = (const float*)d_in[11];
    const float* mu_b1 = (const float*)d_in[12];
    const float* mu_w2 = (const float*)d_in[13];
    const float* mu_b2 = (const float*)d_in[14];
    const float* lv_w1 = (const float*)d_in[15];
    const float* lv_b1 = (const float*)d_in[16];
    const float* lv_w2 = (const float*)d_in[17];
    const float* lv_b2 = (const float*)d_in[18];

    float* out = (float*)d_out;
    const size_t OFF_SUB = 0;
    const size_t OFF_REL = 1638400;
    const size_t OFF_X   = 3276800;
    const size_t OFF_MI  = 35276800;
    float* xall = out + OFF_X;

    const int* src = eidx;
    const int* dst = eidx + EE;

    bool fast = (ws_size >= (size_t)101 * 1000 * 1000);

    char* w = (char*)d_ws;
    u8* xq0 = nullptr; u8* xq1 = nullptr; bf16* xtmp = nullptr;
    if (fast) {
        xq0 = (u8*)w; w += (size_t)N_NODES * FD + XPAD;   // 32 MB + pad
        xq1 = (u8*)w; w += (size_t)N_NODES * FD + XPAD;   // 32 MB + pad
    } else {
        xtmp = (bf16*)w; w += (size_t)N_NODES * DD * 2;   // 16 MB
    }
    u8*   kwb  = (u8*)w;    w += (size_t)N_NODES * FD + XPAD;   // 32 MB + pad
    float* r0p = (float*)w; w += NRELS * RPAD * 4;
    float* r1  = (float*)w; w += NRELS * RPAD * 4;
    u32* ep    = (u32*)w;   w += EE * 4;
    int* count = (int*)w;   w += N_NODES * 4;             // doubles as scatter cursor
    int* offs  = (int*)w;   w += (N_NODES + 16) * 4;
    double* loss = (double*)w; w += 256;

    // Bpack (bf16 hi/lo B-fragments, 372 KB) aliases the head of ep (dead until scatter).
    u16* bp = (u16*)ep;

    hipLaunchKernelGGL(zero_kernel, dim3(157), dim3(256), 0, stream, count, loss,
                       fast ? xq0 + (size_t)N_NODES * FD : nullptr,
                       fast ? xq1 + (size_t)N_NODES * FD : nullptr);
    if (fast) hipLaunchKernelGGL(bpack_kernel, dim3(23), dim3(256), 0, stream, cw_w, bp);
    hipLaunchKernelGGL(pca_kernel, dim3(13, 2500), dim3(64), 0, stream,
                       init_embed, pca_w, pca_b, xq0, xall, fast ? 0 : 1);
    if (fast) hipLaunchKernelGGL(kw_mfma, dim3(1250), dim3(256), 0, stream, xq0, bp, kwb);
    else      hipLaunchKernelGGL(kw_old, dim3(10000), dim3(256), 0, stream, xall, cw_w, kwb);
    hipLaunchKernelGGL(count_kernel, dim3(3125), dim3(256), 0, stream, dst, count);
    hipLaunchKernelGGL(scan_kernel, dim3(1), dim3(1024), 0, stream, count, offs);
    hipLaunchKernelGGL(scatter_kernel, dim3(3125), dim3(256), 0, stream, src, dst, etyp, offs, count, ep);
    hipLaunchKernelGGL(r0pad_kernel, dim3(700), dim3(256), 0, stream, init_rel, r0p);
    hipLaunchKernelGGL(rmul_kernel, dim3(800), dim3(256), 0, stream, init_rel, w_rel, r1);

    if (fast) {
        hipLaunchKernelGGL(agg_fp8, dim3(10000), dim3(256), 0, stream,
                           xq0, kwb, r0p, offs, ep, xq1, (float*)nullptr, 0);
        hipLaunchKernelGGL(agg_fp8, dim3(10000), dim3(256), 0, stream,
                           xq1, kwb, r1, offs, ep, (u8*)nullptr, xall, 1);
    } else {
        for (int f = 0; f < FF; f++) {
            hipLaunchKernelGGL(agg_sliced, dim3(10000), dim3(256), 0, stream,
                               xall, kwb, r0p, offs, ep, xtmp, f);
            hipLaunchKernelGGL(copyback_kernel, dim3(31250), dim3(256), 0, stream, xtmp, xall, f);
        }
        for (int f = 0; f < FF; f++) {
            hipLaunchKernelGGL(agg_sliced, dim3(10000), dim3(256), 0, stream,
                               xall, kwb, r1, offs, ep, xtmp, f);
            hipLaunchKernelGGL(copyback_kernel, dim3(31250), dim3(256), 0, stream, xtmp, xall, f);
        }
    }

    hipLaunchKernelGGL(subemb_kernel, dim3(6400), dim3(256), 0, stream, xall, sub, out + OFF_SUB);
    hipLaunchKernelGGL(relemb_kernel, dim3(6400), dim3(256), 0, stream, init_rel, rel, out + OFF_REL);
    hipLaunchKernelGGL(club_kernel, dim3(1024, 6), dim3(256), 0, stream, out + OFF_SUB, perm,
                       mu_w1, mu_b1, mu_w2, mu_b2, lv_w1, lv_b1, lv_w2, lv_b2, loss);
    hipLaunchKernelGGL(loss_out_kernel, dim3(1), dim3(64), 0, stream, loss, out + OFF_MI);
}

// Round 8
// 1119.636 us; speedup vs baseline: 4.0980x; 4.0980x over previous
//
#include <hip/hip_runtime.h>
#include <hip/hip_bf16.h>

#define N_NODES 40000
#define INIT_D  100
#define DD      200
#define FF      4
#define EE      800000
#define NRELS   800
#define BB      2048
#define H2D     100
#define FD      800   // F*D
#define RPAD    224   // padded r row (floats), zeros at 200..223
#define XPAD    256   // byte pad after fp8 x / kw buffers (zeroed for x)

typedef __hip_bfloat16 bf16;
typedef unsigned char u8;
typedef unsigned short u16;
typedef unsigned int u32;
typedef float floatx2 __attribute__((ext_vector_type(2)));
typedef float floatx4 __attribute__((ext_vector_type(4)));
typedef u32 u32x2 __attribute__((ext_vector_type(2)));
typedef short bshort8 __attribute__((ext_vector_type(8)));   // 8 bf16 for MFMA A/B

#define XSCALE 256.f
#define XINV   (1.f / 256.f)

__device__ __forceinline__ float b2f(bf16 v) { return __bfloat162float(v); }

__device__ __forceinline__ void fp8x4_dec(u32 q, float* o) {
    floatx2 lo = __builtin_amdgcn_cvt_pk_f32_fp8((int)q, false);
    floatx2 hi = __builtin_amdgcn_cvt_pk_f32_fp8((int)q, true);
    o[0] = lo.x; o[1] = lo.y; o[2] = hi.x; o[3] = hi.y;
}

__device__ __forceinline__ u32 fp8x4_enc(float v0, float v1, float v2, float v3) {
    int o = 0;
    o = __builtin_amdgcn_cvt_pk_fp8_f32(v0, v1, o, false);
    o = __builtin_amdgcn_cvt_pk_fp8_f32(v2, v3, o, true);
    return (u32)o;
}

// sum over each 16-lane group via DPP (pure VALU, no LDS pipe).
__device__ __forceinline__ float red16(float v) {
    int t;
    t = __builtin_amdgcn_update_dpp(0, __float_as_int(v), 0xB1, 0xF, 0xF, true);
    v += __int_as_float(t);
    t = __builtin_amdgcn_update_dpp(0, __float_as_int(v), 0x4E, 0xF, 0xF, true);
    v += __int_as_float(t);
    t = __builtin_amdgcn_update_dpp(0, __float_as_int(v), 0x124, 0xF, 0xF, true);
    v += __int_as_float(t);
    t = __builtin_amdgcn_update_dpp(0, __float_as_int(v), 0x128, 0xF, 0xF, true);
    v += __int_as_float(t);
    return v;
}

// fp8x8 (two u32) -> bf16x8 (exact: e4m3 subset of bf16)
__device__ __forceinline__ bshort8 fp8x8_bf16(u32x2 q) {
    float f[8];
    fp8x4_dec(q.x, f); fp8x4_dec(q.y, f + 4);
    bshort8 r;
#pragma unroll
    for (int j = 0; j < 8; j++) r[j] = (short)(__float_as_uint(f[j]) >> 16);
    return r;
}

// ---------------- setup ----------------
__global__ __launch_bounds__(256) void zero_kernel(int* count, double* loss, u8* pad0, u8* pad1) {
    int idx = blockIdx.x * 256 + threadIdx.x;
    if (idx < N_NODES) count[idx] = 0;
    if (idx == 0) *loss = 0.0;
    if (idx < 64 && pad0) ((u32*)pad0)[idx] = 0u;
    if (idx < 64 && pad1) ((u32*)pad1)[idx] = 0u;
}

// ---------------- x0 = tanh(init_embed @ pca_w + pca_b) ----------------
__global__ __launch_bounds__(64) void pca_kernel(const float* __restrict__ emb,
                                                 const float* __restrict__ pw,
                                                 const float* __restrict__ pb,
                                                 u8* __restrict__ xq,
                                                 float* __restrict__ xf,
                                                 int mode) {
    __shared__ float es[INIT_D][18];
    int r0 = blockIdx.y * 16;
    int c  = blockIdx.x * 64 + threadIdx.x;
    for (int idx = threadIdx.x; idx < 16 * INIT_D; idx += 64) {
        int r = idx / INIT_D, k = idx % INIT_D;
        es[k][r] = emb[(size_t)(r0 + r) * INIT_D + k];
    }
    __syncthreads();
    if (c >= FD) return;
    floatx2 acc[8];
#pragma unroll
    for (int i = 0; i < 8; i++) acc[i] = (floatx2){0.f, 0.f};
    for (int k = 0; k < INIT_D; k++) {
        float w = pw[k * FD + c];
        floatx2 w2 = (floatx2){w, w};
#pragma unroll
        for (int i = 0; i < 8; i++) acc[i] += *(const floatx2*)&es[k][2 * i] * w2;
    }
    float bias = pb[c];
#pragma unroll
    for (int r = 0; r < 16; r++) {
        float a = (r & 1) ? acc[r >> 1].y : acc[r >> 1].x;
        float v = tanhf(a + bias);
        if (mode == 0) {
            int t8 = __builtin_amdgcn_cvt_pk_fp8_f32(v * XSCALE, 0.f, 0, false);
            xq[(size_t)(r0 + r) * FD + c] = (u8)(t8 & 0xFF);
        } else {
            xf[(size_t)(r0 + r) * FD + c] = v;
        }
    }
}

// ---------------- B-pack: cw -> MFMA B-fragments, s-major for LDS staging -------
// bp layout [s][t][hl][lane][8] u16: index (((s*13+t)*2+hl)*64+lane)*8.
// B[k][col]: col = t*16 + (lane&15), k = s*32 + (lane>>4)*8 + j; zero outside 200x200.
__global__ __launch_bounds__(256) void bpack_kernel(const float* __restrict__ cw,
                                                    u16* __restrict__ bp) {
    int w = (blockIdx.x * 256 + threadIdx.x) >> 6;
    int lane = threadIdx.x & 63;
    if (w >= 91) return;
    int t = w / 7, s = w % 7;
    int col = t * 16 + (lane & 15);
    int g = lane >> 4;
    bshort8 hv, lv;
#pragma unroll
    for (int j = 0; j < 8; j++) {
        int k = s * 32 + g * 8 + j;
        float v = (k < DD && col < DD) ? cw[k * DD + col] : 0.f;
        u32 b = __float_as_uint(v);
        u32 rb = b + 0x7FFFu + ((b >> 16) & 1u);
        u16 h = (u16)(rb >> 16);
        float hf = __uint_as_float(((u32)h) << 16);
        float lo = v - hf;
        u32 lb = __float_as_uint(lo);
        lb += 0x7FFFu + ((lb >> 16) & 1u);
        hv[j] = (short)h;
        lv[j] = (short)(lb >> 16);
    }
    size_t base = ((size_t)((s * 13 + t) * 2) * 64 + lane) * 8;
    *(bshort8*)(bp + base) = hv;          // hl = 0 (hi)
    *(bshort8*)(bp + base + 512) = lv;    // hl = 1 (lo)
}

// ---------------- kw via MFMA + LDS-staged B ----------------
// Per s-step the block stages the 26 KB B-slab (13 t x hi/lo) into LDS once;
// all 4 waves consume from LDS. Same MFMA order as round-3 -> identical numerics.
__global__ __launch_bounds__(256) void kw_mfma(const u8* __restrict__ xq,
                                               const u16* __restrict__ bp,
                                               u8* __restrict__ kwout) {
    __shared__ u16 bs[13312];   // 26,624 B = 13 t x 2 x 64 x 8 u16
    int wv = threadIdx.x >> 6, lane = threadIdx.x & 63;
    int Mbase = blockIdx.x * 128 + wv * 32;
    int g = lane >> 4, c16 = lane & 15;
    floatx4 acc[2][13];
#pragma unroll
    for (int m = 0; m < 2; m++)
#pragma unroll
        for (int t = 0; t < 13; t++) acc[m][t] = (floatx4){0.f, 0.f, 0.f, 0.f};

    const u8* a0p = xq + (size_t)(Mbase + c16) * DD + g * 8;
    const u8* a1p = a0p + 16 * DD;
    u32x2 qa = *(const u32x2*)a0p;
    u32x2 qb = *(const u32x2*)a1p;

    for (int s = 0; s < 7; s++) {
        __syncthreads();   // prior compute done before overwrite
        const floatx4* gs = (const floatx4*)(bp + (size_t)s * 13312);
        floatx4* ld = (floatx4*)bs;
        for (int i = threadIdx.x; i < 1664; i += 256) ld[i] = gs[i];
        __syncthreads();
        bshort8 a0 = fp8x8_bf16(qa);
        bshort8 a1 = fp8x8_bf16(qb);
        if (s < 6) {   // 1-deep A prefetch, overlaps the MFMA block
            qa = *(const u32x2*)(a0p + (s + 1) * 32);
            qb = *(const u32x2*)(a1p + (s + 1) * 32);
        }
#pragma unroll
        for (int t = 0; t < 13; t++) {
            const u16* tb = bs + t * 1024;
            bshort8 bh = *(const bshort8*)(tb + lane * 8);
            bshort8 bl = *(const bshort8*)(tb + 512 + lane * 8);
            acc[0][t] = __builtin_amdgcn_mfma_f32_16x16x32_bf16(a0, bh, acc[0][t], 0, 0, 0);
            acc[1][t] = __builtin_amdgcn_mfma_f32_16x16x32_bf16(a1, bh, acc[1][t], 0, 0, 0);
            acc[0][t] = __builtin_amdgcn_mfma_f32_16x16x32_bf16(a0, bl, acc[0][t], 0, 0, 0);
            acc[1][t] = __builtin_amdgcn_mfma_f32_16x16x32_bf16(a1, bl, acc[1][t], 0, 0, 0);
        }
    }

    int rq = g * 4;
#pragma unroll
    for (int m = 0; m < 2; m++) {
#pragma unroll
        for (int t = 0; t < 13; t++) {
            int col = t * 16 + c16;
            if (col >= DD) continue;
            floatx4 a = acc[m][t];
            float v0 = a.x * XINV, v1 = a.y * XINV, v2 = a.z * XINV, v3 = a.w * XINV;
            v0 = v0 > 0.f ? v0 : 0.2f * v0;
            v1 = v1 > 0.f ? v1 : 0.2f * v1;
            v2 = v2 > 0.f ? v2 : 0.2f * v2;
            v3 = v3 > 0.f ? v3 : 0.2f * v3;
            float mx = fmaxf(fmaxf(v0, v1), fmaxf(v2, v3));
            float e0 = __expf(v0 - mx), e1 = __expf(v1 - mx);
            float e2 = __expf(v2 - mx), e3 = __expf(v3 - mx);
            float inv = 1.f / (e0 + e1 + e2 + e3);
            size_t base = (size_t)(Mbase + m * 16 + rq) * DD + col;
            kwout[base]           = (u8)(e0 * inv * 255.f + 0.5f);
            kwout[base + DD]      = (u8)(e1 * inv * 255.f + 0.5f);
            kwout[base + 2 * DD]  = (u8)(e2 * inv * 255.f + 0.5f);
            kwout[base + 3 * DD]  = (u8)(e3 * inv * 255.f + 0.5f);
        }
    }
}

// ---------------- kw fallback: wave-per-node, f32 x ----------------
__global__ __launch_bounds__(256) void kw_old(const float* __restrict__ x,
                                              const float* __restrict__ cw,
                                              u8* __restrict__ kw) {
    int wave = threadIdx.x >> 6, lane = threadIdx.x & 63;
    int n = blockIdx.x * 4 + wave;
    const float* xp = x + (size_t)n * FD;
    float acc[4][4];
#pragma unroll
    for (int f = 0; f < 4; f++)
#pragma unroll
        for (int i = 0; i < 4; i++) acc[f][i] = 0.f;
    for (int k = 0; k < DD; k++) {
        float xv0 = xp[k], xv1 = xp[DD + k];
        float xv2 = xp[2 * DD + k], xv3 = xp[3 * DD + k];
#pragma unroll
        for (int i = 0; i < 4; i++) {
            int d = i * 64 + lane;
            float w = (d < DD) ? cw[k * DD + d] : 0.f;
            acc[0][i] += xv0 * w; acc[1][i] += xv1 * w;
            acc[2][i] += xv2 * w; acc[3][i] += xv3 * w;
        }
    }
    u8* kwp = kw + (size_t)n * FD;
#pragma unroll
    for (int i = 0; i < 4; i++) {
        int d = i * 64 + lane;
        if (d >= DD) continue;
        float v0 = acc[0][i], v1 = acc[1][i], v2 = acc[2][i], v3 = acc[3][i];
        v0 = v0 > 0.f ? v0 : 0.2f * v0;
        v1 = v1 > 0.f ? v1 : 0.2f * v1;
        v2 = v2 > 0.f ? v2 : 0.2f * v2;
        v3 = v3 > 0.f ? v3 : 0.2f * v3;
        float m = fmaxf(fmaxf(v0, v1), fmaxf(v2, v3));
        float e0 = __expf(v0 - m), e1 = __expf(v1 - m), e2 = __expf(v2 - m), e3 = __expf(v3 - m);
        float inv = 1.f / (e0 + e1 + e2 + e3);
        kwp[d]          = (u8)(e0 * inv * 255.f + 0.5f);
        kwp[DD + d]     = (u8)(e1 * inv * 255.f + 0.5f);
        kwp[2 * DD + d] = (u8)(e2 * inv * 255.f + 0.5f);
        kwp[3 * DD + d] = (u8)(e3 * inv * 255.f + 0.5f);
    }
}

// ---------------- CSR build (packed: etype<<16 | src) ----------------
__global__ __launch_bounds__(256) void count_kernel(const int* __restrict__ dst, int* count) {
    int e = blockIdx.x * 256 + threadIdx.x;
    atomicAdd(&count[dst[e]], 1);
}

// shfl-based scan; also zeroes count[] so it can be reused as the scatter cursor.
__global__ __launch_bounds__(1024) void scan_kernel(int* __restrict__ count, int* __restrict__ offs) {
    __shared__ int wsums[16];
    __shared__ int carry_s;
    int tid = threadIdx.x;
    int wv = tid >> 6, lane = tid & 63;
    if (tid == 0) { carry_s = 0; offs[0] = 0; }
    __syncthreads();
    for (int base = 0; base < 40960; base += 1024) {
        int i = base + tid;
        int v = (i < N_NODES) ? count[i] : 0;
        if (i < N_NODES) count[i] = 0;
        int x = v;
#pragma unroll
        for (int off = 1; off < 64; off <<= 1) {
            int y = __shfl_up(x, off, 64);
            if (lane >= off) x += y;
        }
        if (lane == 63) wsums[wv] = x;
        __syncthreads();
        if (wv == 0) {
            int s = (lane < 16) ? wsums[lane] : 0;
#pragma unroll
            for (int off = 1; off < 16; off <<= 1) {
                int y = __shfl_up(s, off, 64);
                if (lane >= off) s += y;
            }
            if (lane < 16) wsums[lane] = s;
        }
        __syncthreads();
        int add = carry_s + (wv > 0 ? wsums[wv - 1] : 0);
        int incl = x + add;
        if (i < N_NODES) offs[i + 1] = incl;
        __syncthreads();
        if (tid == 1023) carry_s = incl;
        __syncthreads();
    }
}

__global__ __launch_bounds__(256) void scatter_kernel(const int* __restrict__ src,
                                                      const int* __restrict__ dst,
                                                      const int* __restrict__ etyp,
                                                      const int* __restrict__ offs,
                                                      int* cursor,
                                                      u32* __restrict__ ep) {
    int e = blockIdx.x * 256 + threadIdx.x;
    int d = dst[e];
    int p = offs[d] + atomicAdd(&cursor[d], 1);
    ep[p] = ((u32)etyp[e] << 16) | (u32)src[e];
}

// ---------------- r padding ----------------
__global__ __launch_bounds__(256) void r0pad_kernel(const float* __restrict__ r0,
                                                    float* __restrict__ rp) {
    int idx = blockIdx.x * 256 + threadIdx.x;   // 800*224 = 179200 exactly
    int n = idx / RPAD, d = idx % RPAD;
    rp[idx] = (d < DD) ? r0[n * DD + d] : 0.f;
}

__global__ __launch_bounds__(256) void rmul_kernel(const float* __restrict__ r0,
                                                   const float* __restrict__ w,
                                                   float* __restrict__ r1) {
    __shared__ float row[DD];
    int n = blockIdx.x;
    if (threadIdx.x < DD) row[threadIdx.x] = r0[n * DD + threadIdx.x];
    __syncthreads();
    int d = threadIdx.x;
    if (d < DD) {
        float acc = 0.f;
        for (int k = 0; k < DD; k++) acc += row[k] * w[k * DD + d];
        r1[n * RPAD + d] = acc;
    } else if (d < RPAD) {
        r1[n * RPAD + d] = 0.f;
    }
}

// ---------------- fast agg: 16-lane f-groups, scalar edge broadcast, 2-slot pipe --
// (round-3 version, benched 223 us/layer; NO min-waves hint — (256,8) forced
// VGPR 64->32 and spilled: FETCH 386MB->4.5GB, 223->1968 us. Guideline 1 caveat.)
__global__ __launch_bounds__(256) void agg_fp8(const u8* __restrict__ xin,
                                               const u8* __restrict__ kwv,
                                               const float* __restrict__ r,
                                               const int* __restrict__ offs,
                                               const u32* __restrict__ ep,
                                               u8* __restrict__ xoq,
                                               float* __restrict__ xof,
                                               int mode) {
    int n    = blockIdx.x * 4 + (threadIdx.x >> 6);   // 40000 waves
    int lane = threadIdx.x & 63;
    int f    = lane >> 4;
    int k    = lane & 15;
    bool act = k < 13;
    int xoff = f * DD + k * 16;
    int roffc = k * 16; if (roffc > 200) roffc = 200;   // lanes 13..15 -> zero pad

    float xdf[16];
    {
        const u8* xdp = xin + (size_t)n * FD + xoff;
        u32x2 a = *(const u32x2*)xdp;
        u32x2 b = *(const u32x2*)(xdp + 8);
        fp8x4_dec(a.x, xdf); fp8x4_dec(a.y, xdf + 4);
        fp8x4_dec(b.x, xdf + 8); fp8x4_dec(b.y, xdf + 12);
    }
    floatx2 xd2[8];
#pragma unroll
    for (int j = 0; j < 8; j++) xd2[j] = (floatx2){xdf[2 * j], xdf[2 * j + 1]};

    floatx2 A[8];
#pragma unroll
    for (int j = 0; j < 8; j++) A[j] = (floatx2){0.f, 0.f};
    float Sm = 0.f;

    int e0 = offs[n], e1 = offs[n + 1];

#define ISSUE(QA, QB, R0, R1, R2, R3, JJ) do {                                  \
    u32 wrd_ = (u32)__builtin_amdgcn_readlane((int)epv, (JJ));                  \
    int s_ = (int)(wrd_ & 0xFFFFu), t_ = (int)(wrd_ >> 16);                     \
    const u8* xsp_ = xin + (size_t)s_ * FD;                                     \
    const float* rp_ = r + (size_t)t_ * RPAD + roffc;                           \
    QA = *(const u32x2*)(xsp_ + xoff);                                          \
    QB = *(const u32x2*)(xsp_ + xoff + 8);                                      \
    const floatx4* r4_ = (const floatx4*)rp_;                                   \
    R0 = r4_[0]; R1 = r4_[1]; R2 = r4_[2]; R3 = r4_[3];                         \
} while (0)

#define COMPUTE(QA, QB, R0, R1, R2, R3) do {                                    \
    float xsf_[16];                                                             \
    fp8x4_dec(QA.x, xsf_);     fp8x4_dec(QA.y, xsf_ + 4);                       \
    fp8x4_dec(QB.x, xsf_ + 8); fp8x4_dec(QB.y, xsf_ + 12);                      \
    floatx2 rr_[8];                                                             \
    rr_[0] = (floatx2){R0.x, R0.y}; rr_[1] = (floatx2){R0.z, R0.w};             \
    rr_[2] = (floatx2){R1.x, R1.y}; rr_[3] = (floatx2){R1.z, R1.w};             \
    rr_[4] = (floatx2){R2.x, R2.y}; rr_[5] = (floatx2){R2.z, R2.w};             \
    rr_[6] = (floatx2){R3.x, R3.y}; rr_[7] = (floatx2){R3.z, R3.w};             \
    floatx2 mm_[8];                                                             \
    floatx2 ps_ = (floatx2){0.f, 0.f};                                          \
    _Pragma("unroll")                                                           \
    for (int j_ = 0; j_ < 8; j_++) {                                            \
        floatx2 xs2_ = (floatx2){xsf_[2 * j_], xsf_[2 * j_ + 1]};               \
        mm_[j_] = xs2_ * rr_[j_];                                               \
        ps_ += mm_[j_] * xd2[j_];                                               \
    }                                                                           \
    float p_ = red16(ps_.x + ps_.y);                                            \
    float q_ = p_ * (XINV * XINV);                                              \
    float lg_ = fmaxf(q_, 0.2f * q_);                                           \
    float wg_ = __expf(lg_);                                                    \
    Sm += wg_;                                                                  \
    floatx2 w2_ = (floatx2){wg_, wg_};                                          \
    _Pragma("unroll")                                                           \
    for (int j_ = 0; j_ < 8; j_++) A[j_] += w2_ * mm_[j_];                      \
} while (0)

    for (int cb = e0; cb < e1; cb += 64) {
        int cnt = e1 - cb; if (cnt > 64) cnt = 64;
        u32 epv = ep[cb + (lane < cnt ? lane : cnt - 1)];
        u32x2 qaA, qbA, qaB, qbB;
        floatx4 rA0, rA1, rA2, rA3, rB0, rB1, rB2, rB3;
        ISSUE(qaA, qbA, rA0, rA1, rA2, rA3, 0);
        if (cnt > 1) ISSUE(qaB, qbB, rB0, rB1, rB2, rB3, 1);
        int m2 = cnt & ~1;
        for (int ii = 0; ii < m2; ii += 2) {
            COMPUTE(qaA, qbA, rA0, rA1, rA2, rA3);
            if (ii + 2 < cnt) ISSUE(qaA, qbA, rA0, rA1, rA2, rA3, ii + 2);
            COMPUTE(qaB, qbB, rB0, rB1, rB2, rB3);
            if (ii + 3 < cnt) ISSUE(qaB, qbB, rB0, rB1, rB2, rB3, ii + 3);
        }
        if (cnt & 1) COMPUTE(qaA, qbA, rA0, rA1, rA2, rA3);
    }
#undef ISSUE
#undef COMPUTE

    float inv = 1.f / (Sm + 1e-16f);
    u32 kws[4];
    {
        const u8* kwp = kwv + (size_t)n * FD + xoff;
        u32x2 ka = *(const u32x2*)kwp;
        u32x2 kb = *(const u32x2*)(kwp + 8);
        kws[0] = ka.x; kws[1] = ka.y; kws[2] = kb.x; kws[3] = kb.y;
    }
    float v[16];
#pragma unroll
    for (int j = 0; j < 16; j++) {
        float kv = (float)((kws[j >> 2] >> ((j & 3) * 8)) & 0xFF) * (1.f / 255.f);
        float Aj = (j & 1) ? A[j >> 1].y : A[j >> 1].x;
        v[j] = tanhf(Aj * inv * XINV) * kv;   // A scaled by S
    }
    if (mode == 0) {
        if (act) {
            u32 o0 = fp8x4_enc(v[0] * XSCALE, v[1] * XSCALE, v[2] * XSCALE, v[3] * XSCALE);
            u32 o1 = fp8x4_enc(v[4] * XSCALE, v[5] * XSCALE, v[6] * XSCALE, v[7] * XSCALE);
            u32 o2 = fp8x4_enc(v[8] * XSCALE, v[9] * XSCALE, v[10] * XSCALE, v[11] * XSCALE);
            u32 o3 = fp8x4_enc(v[12] * XSCALE, v[13] * XSCALE, v[14] * XSCALE, v[15] * XSCALE);
            u8* op = xoq + (size_t)n * FD + xoff;
            *(u32x2*)op = (u32x2){o0, o1};
            if (k < 12) *(u32x2*)(op + 8) = (u32x2){o2, o3};
        }
    } else {
        if (act) {
            float* op = xof + (size_t)n * FD + xoff;
            *(floatx4*)op       = (floatx4){v[0], v[1], v[2], v[3]};
            *(floatx4*)(op + 4) = (floatx4){v[4], v[5], v[6], v[7]};
            if (k < 12) {
                *(floatx4*)(op + 8)  = (floatx4){v[8], v[9], v[10], v[11]};
                *(floatx4*)(op + 12) = (floatx4){v[12], v[13], v[14], v[15]};
            }
        }
    }
}

// ---------------- fallback sliced agg (f32, RPAD-strided r) + copyback ----------------
__global__ __launch_bounds__(256) void agg_sliced(const float* __restrict__ xall,
                                                  const u8* __restrict__ kw,
                                                  const float* __restrict__ r,
                                                  const int* __restrict__ offs,
                                                  const u32* __restrict__ ep,
                                                  bf16* __restrict__ xtmp,
                                                  int f) {
    int n    = blockIdx.x * 4 + (threadIdx.x >> 6);
    int lane = threadIdx.x & 63;
    const float* xdp = xall + (size_t)n * FD + f * DD;
    float xd[4];
#pragma unroll
    for (int i = 0; i < 4; i++) {
        int d = i * 64 + lane;
        xd[i] = (d < DD) ? xdp[d] : 0.f;
    }
    float M = -INFINITY, S = 0.f;
    float A0 = 0.f, A1 = 0.f, A2 = 0.f, A3 = 0.f;
    int e0 = offs[n], e1 = offs[n + 1];
    for (int e = e0; e < e1; ++e) {
        u32 wrd = ep[e];
        int s = wrd & 0xFFFF, t = wrd >> 16;
        const float* xsp = xall + (size_t)s * FD + f * DD;
        const float* rp = r + (size_t)t * RPAD;
        float mm[4];
        float p = 0.f;
#pragma unroll
        for (int i = 0; i < 4; i++) {
            int d = i * 64 + lane;
            float xs = (d < DD) ? xsp[d] : 0.f;
            float rrv = (d < DD) ? rp[d] : 0.f;
            mm[i] = xs * rrv;
            p += mm[i] * xd[i];
        }
#pragma unroll
        for (int o = 32; o > 0; o >>= 1) p += __shfl_xor(p, o, 64);
        float logit = p > 0.f ? p : 0.2f * p;
        float nm = fmaxf(M, logit);
        float sc = __expf(M - nm);
        float w  = __expf(logit - nm);
        S  = S * sc + w;
        A0 = A0 * sc + w * mm[0];
        A1 = A1 * sc + w * mm[1];
        A2 = A2 * sc + w * mm[2];
        A3 = A3 * sc + w * mm[3];
        M = nm;
    }
    float inv = 1.f / (S + 1e-16f);
    const u8* kwp = kw + (size_t)n * FD + f * DD;
    bf16* xo = xtmp + (size_t)n * DD;
    float A[4] = {A0, A1, A2, A3};
#pragma unroll
    for (int i = 0; i < 4; i++) {
        int d = i * 64 + lane;
        if (d < DD) {
            float kv = (float)kwp[d] * (1.f / 255.f);
            xo[d] = __float2bfloat16(tanhf(A[i] * inv) * kv);
        }
    }
}

__global__ __launch_bounds__(256) void copyback_kernel(const bf16* __restrict__ xtmp,
                                                       float* __restrict__ xall, int f) {
    int idx = blockIdx.x * 256 + threadIdx.x;   // 8,000,000
    int n = idx / DD, d = idx % DD;
    xall[(size_t)n * FD + f * DD + d] = b2f(xtmp[idx]);
}

// ---------------- outputs (f32) ----------------
__global__ __launch_bounds__(256) void subemb_kernel(const float* __restrict__ x,
                                                     const int* __restrict__ sub,
                                                     float* __restrict__ out) {
    int idx = blockIdx.x * 256 + threadIdx.x;   // 1,638,400
    int b = idx / FD, c = idx % FD;
    out[idx] = x[(size_t)sub[b] * FD + c];
}

__global__ __launch_bounds__(256) void relemb_kernel(const float* __restrict__ ir,
                                                     const int* __restrict__ rel,
                                                     float* __restrict__ out) {
    int idx = blockIdx.x * 256 + threadIdx.x;   // 1,638,400
    int b = idx / FD, d = idx % DD;
    out[idx] = ir[(size_t)rel[b] * DD + d];
}

// ---------------- CLUB loss: 2 rows/block, mu/lv phase-1 in parallel ----------
__global__ __launch_bounds__(256) void club_kernel(const float* __restrict__ se,
                                                   const int* __restrict__ perm,
                                                   const float* __restrict__ mu_w1, const float* __restrict__ mu_b1,
                                                   const float* __restrict__ mu_w2, const float* __restrict__ mu_b2,
                                                   const float* __restrict__ lv_w1, const float* __restrict__ lv_b1,
                                                   const float* __restrict__ lv_w2, const float* __restrict__ lv_b2,
                                                   double* loss) {
    const int PI[6] = {0, 0, 0, 1, 1, 2};
    const int PJ[6] = {1, 2, 3, 2, 3, 3};
    int p = blockIdx.y;
    int i = PI[p], j = PJ[p];
    __shared__ float xi[DD], yj[DD], yjp[DD], h1m[H2D], h1v[H2D];
    __shared__ float wsum[4];
    float psum = 0.f;
    int tid = threadIdx.x;
    for (int rr = 0; rr < 2; ++rr) {
        int b = blockIdx.x * 2 + rr;
        int bp = perm[b];
        if (tid < DD) {
            xi[tid]  = se[(size_t)b * FD + i * DD + tid];
            yj[tid]  = se[(size_t)b * FD + j * DD + tid];
            yjp[tid] = se[(size_t)bp * FD + j * DD + tid];
        }
        __syncthreads();
        if (tid < H2D) {
            int c = tid;
            float a1 = mu_b1[p * H2D + c];
            for (int d = 0; d < DD; d++)
                a1 += xi[d] * mu_w1[(size_t)p * DD * H2D + d * H2D + c];
            h1m[c] = fmaxf(a1, 0.f);
        } else if (tid >= 128 && tid < 128 + H2D) {
            int c = tid - 128;
            float a2 = lv_b1[p * H2D + c];
            for (int d = 0; d < DD; d++)
                a2 += xi[d] * lv_w1[(size_t)p * DD * H2D + d * H2D + c];
            h1v[c] = fmaxf(a2, 0.f);
        }
        __syncthreads();
        if (tid < DD) {
            int d = tid;
            float m = mu_b2[p * DD + d];
            float v = lv_b2[p * DD + d];
            for (int c = 0; c < H2D; c++) {
                m += h1m[c] * mu_w2[(size_t)p * H2D * DD + c * DD + d];
                v += h1v[c] * lv_w2[(size_t)p * H2D * DD + c * DD + d];
            }
            float lv = tanhf(v);
            float ivr = __expf(-lv);
            float d1 = m - yj[d], d2 = m - yjp[d];
            psum += (d2 * d2 - d1 * d1) * ivr;
        }
        __syncthreads();
    }
    float v = psum;
#pragma unroll
    for (int o = 32; o > 0; o >>= 1) v += __shfl_xor(v, o, 64);
    if ((tid & 63) == 0) wsum[tid >> 6] = v;
    __syncthreads();
    if (tid == 0) {
        double t = (double)wsum[0] + (double)wsum[1] + (double)wsum[2] + (double)wsum[3];
        atomicAdd(loss, t / (2.0 * (double)BB));
    }
}

__global__ void loss_out_kernel(const double* loss, float* out) {
    if (threadIdx.x == 0 && blockIdx.x == 0)
        out[0] = (float)(*loss);
}

// ---------------- launch ----------------
extern "C" void kernel_launch(void* const* d_in, const int* in_sizes, int n_in,
                              void* d_out, int out_size, void* d_ws, size_t ws_size,
                              hipStream_t stream) {
    const int* sub  = (const int*)d_in[0];
    const int* rel  = (const int*)d_in[1];
    const int* eidx = (const int*)d_in[2];
    const int* etyp = (const int*)d_in[3];
    const int* perm = (const int*)d_in[4];
    const float* init_embed = (const float*)d_in[5];
    const float* init_rel   = (const float*)d_in[6];
    const float* pca_w = (const float*)d_in[7];
    const float* pca_b = (const float*)d_in[8];
    const float* cw_w  = (const float*)d_in[9];
    const float* w_rel = (const float*)d_in[10];
    const float* mu_w1 = (const float*)d_in[11];
    const float* mu_b1 = (const float*)d_in[12];
    const float* mu_w2 = (const float*)d_in[13];
    const float* mu_b2 = (const float*)d_in[14];
    const float* lv_w1 = (const float*)d_in[15];
    const float* lv_b1 = (const float*)d_in[16];
    const float* lv_w2 = (const float*)d_in[17];
    const float* lv_b2 = (const float*)d_in[18];

    float* out = (float*)d_out;
    const size_t OFF_SUB = 0;
    const size_t OFF_REL = 1638400;
    const size_t OFF_X   = 3276800;
    const size_t OFF_MI  = 35276800;
    float* xall = out + OFF_X;

    const int* src = eidx;
    const int* dst = eidx + EE;

    bool fast = (ws_size >= (size_t)101 * 1000 * 1000);

    char* w = (char*)d_ws;
    u8* xq0 = nullptr; u8* xq1 = nullptr; bf16* xtmp = nullptr;
    if (fast) {
        xq0 = (u8*)w; w += (size_t)N_NODES * FD + XPAD;   // 32 MB + pad
        xq1 = (u8*)w; w += (size_t)N_NODES * FD + XPAD;   // 32 MB + pad
    } else {
        xtmp = (bf16*)w; w += (size_t)N_NODES * DD * 2;   // 16 MB
    }
    u8*   kwb  = (u8*)w;    w += (size_t)N_NODES * FD + XPAD;   // 32 MB + pad
    float* r0p = (float*)w; w += NRELS * RPAD * 4;
    float* r1  = (float*)w; w += NRELS * RPAD * 4;
    u32* ep    = (u32*)w;   w += EE * 4;
    int* count = (int*)w;   w += N_NODES * 4;             // doubles as scatter cursor
    int* offs  = (int*)w;   w += (N_NODES + 16) * 4;
    double* loss = (double*)w; w += 256;

    // Bpack (bf16 hi/lo B-fragments, 372 KB) aliases the head of ep (dead until scatter).
    u16* bp = (u16*)ep;

    hipLaunchKernelGGL(zero_kernel, dim3(157), dim3(256), 0, stream, count, loss,
                       fast ? xq0 + (size_t)N_NODES * FD : nullptr,
                       fast ? xq1 + (size_t)N_NODES * FD : nullptr);
    if (fast) hipLaunchKernelGGL(bpack_kernel, dim3(23), dim3(256), 0, stream, cw_w, bp);
    hipLaunchKernelGGL(pca_kernel, dim3(13, 2500), dim3(64), 0, stream,
                       init_embed, pca_w, pca_b, xq0, xall, fast ? 0 : 1);
    if (fast) hipLaunchKernelGGL(kw_mfma, dim3(1250), dim3(256), 0, stream, xq0, bp, kwb);
    else      hipLaunchKernelGGL(kw_old, dim3(10000), dim3(256), 0, stream, xall, cw_w, kwb);
    hipLaunchKernelGGL(count_kernel, dim3(3125), dim3(256), 0, stream, dst, count);
    hipLaunchKernelGGL(scan_kernel, dim3(1), dim3(1024), 0, stream, count, offs);
    hipLaunchKernelGGL(scatter_kernel, dim3(3125), dim3(256), 0, stream, src, dst, etyp, offs, count, ep);
    hipLaunchKernelGGL(r0pad_kernel, dim3(700), dim3(256), 0, stream, init_rel, r0p);
    hipLaunchKernelGGL(rmul_kernel, dim3(800), dim3(256), 0, stream, init_rel, w_rel, r1);

    if (fast) {
        hipLaunchKernelGGL(agg_fp8, dim3(10000), dim3(256), 0, stream,
                           xq0, kwb, r0p, offs, ep, xq1, (float*)nullptr, 0);
        hipLaunchKernelGGL(agg_fp8, dim3(10000), dim3(256), 0, stream,
                           xq1, kwb, r1, offs, ep, (u8*)nullptr, xall, 1);
    } else {
        for (int f = 0; f < FF; f++) {
            hipLaunchKernelGGL(agg_sliced, dim3(10000), dim3(256), 0, stream,
                               xall, kwb, r0p, offs, ep, xtmp, f);
            hipLaunchKernelGGL(copyback_kernel, dim3(31250), dim3(256), 0, stream, xtmp, xall, f);
        }
        for (int f = 0; f < FF; f++) {
            hipLaunchKernelGGL(agg_sliced, dim3(10000), dim3(256), 0, stream,
                               xall, kwb, r1, offs, ep, xtmp, f);
            hipLaunchKernelGGL(copyback_kernel, dim3(31250), dim3(256), 0, stream, xtmp, xall, f);
        }
    }

    hipLaunchKernelGGL(subemb_kernel, dim3(6400), dim3(256), 0, stream, xall, sub, out + OFF_SUB);
    hipLaunchKernelGGL(relemb_kernel, dim3(6400), dim3(256), 0, stream, init_rel, rel, out + OFF_REL);
    hipLaunchKernelGGL(club_kernel, dim3(1024, 6), dim3(256), 0, stream, out + OFF_SUB, perm,
                       mu_w1, mu_b1, mu_w2, mu_b2, lv_w1, lv_b1, lv_w2, lv_b2, loss);
    hipLaunchKernelGGL(loss_out_kernel, dim3(1), dim3(64), 0, stream, loss, out + OFF_MI);
}